// Round 10
// baseline (247.727 us; speedup 1.0000x reference)
//
#include <hip/hip_runtime.h>

#define NCLS 88
#define DHW (96 * 96 * 96)            // 884736
#define TPB 256                       // 4 waves, 4-way class split
#define WAVES 4
#define CPW 22                        // classes per wave
#define VOX_PER_BLOCK 512             // 8 voxels per lane (2 coalesced float4 groups)
#define BLOCKS_PER_B (DHW / VOX_PER_BLOCK)   // 1728, exact
#define SLOTS 32
#define SMOOTH 1e-5f
#define WS_PER_SLOT 529
// ws layout per slot: [0..176) inter[b*88+c] | [176..352) pred_o | [352..528) cnt | [528] ce

typedef float f2 __attribute__((ext_vector_type(2)));

__device__ __forceinline__ float wave_reduce_sum(float v) {
#pragma unroll
    for (int i = 1; i < 64; i <<= 1)
        v += __shfl_xor(v, i, 64);
    return v;
}

// NOTE: no min-waves arg — __launch_bounds__(TPB,N) forced 64-VGPR + ~1.5 GB
// spill traffic in R4/R6. Plain bound: ~100 VGPR, no scratch.
__global__ __launch_bounds__(TPB)
void seg_loss_main(const float* __restrict__ pred, const int* __restrict__ tgt,
                   float* __restrict__ ws) {
    __shared__ float s_inter[NCLS];
    __shared__ float s_pred[NCLS];
    __shared__ float s_cnt[NCLS];
    __shared__ float s_ce;
    __shared__ float2 s_ex[WAVES][8][64];  // [wave][vox][lane] = {s1_part, et_part}, 16 KB

    const int tid  = threadIdx.x;
    const int lane = tid & 63;
    const int wave = tid >> 6;                 // 0..3
    const int b    = blockIdx.x / BLOCKS_PER_B;
    const int base = (blockIdx.x % BLOCKS_PER_B) * VOX_PER_BLOCK;
    const int cls0 = wave * CPW;
    const float* pb = pred + (size_t)b * NCLS * DHW + (size_t)cls0 * DHW;
    const int*   tb = tgt  + (size_t)b * DHW;

    // ---- targets: 8 voxels per lane, two coalesced int4 groups ----
    const int4 ta = *(const int4*)(tb + base + lane * 4);
    const int4 tB = *(const int4*)(tb + base + 256 + lane * 4);
    const int tv[8] = { ta.x, ta.y, ta.z, ta.w, tB.x, tB.y, tB.z, tB.w };
    bool val[8]; int tc[8]; float vf[8];
#pragma unroll
    for (int v = 0; v < 8; ++v) {
        val[v] = (tv[v] != -1);
        tc[v]  = val[v] ? tv[v] : 0;
        vf[v]  = val[v] ? 1.f : 0.f;
    }

    // ---- pass A: 22 classes x 2 float4 (8 voxels/lane), fp8-packed exps ----
    const float* pa = pb + base + lane * 4;
    const float* pc = pb + base + 256 + lane * 4;
    float s[8]  = {0,0,0,0,0,0,0,0};
    float et[8] = {0,0,0,0,0,0,0,0};
    int efA[CPW], efB[CPW];
#pragma unroll
    for (int c = 0; c < CPW; ++c) {
        const float4 xa = *(const float4*)(pa + (size_t)c * DHW);
        const float4 xb = *(const float4*)(pc + (size_t)c * DHW);
        const float e0 = __expf(xa.x * vf[0]);
        const float e1 = __expf(xa.y * vf[1]);
        const float e2 = __expf(xa.z * vf[2]);
        const float e3 = __expf(xa.w * vf[3]);
        const float e4 = __expf(xb.x * vf[4]);
        const float e5 = __expf(xb.y * vf[5]);
        const float e6 = __expf(xb.z * vf[6]);
        const float e7 = __expf(xb.w * vf[7]);
        s[0] += e0; s[1] += e1; s[2] += e2; s[3] += e3;
        s[4] += e4; s[5] += e5; s[6] += e6; s[7] += e7;
        const int cc = cls0 + c;
        et[0] = (cc == tc[0]) ? e0 : et[0];
        et[1] = (cc == tc[1]) ? e1 : et[1];
        et[2] = (cc == tc[2]) ? e2 : et[2];
        et[3] = (cc == tc[3]) ? e3 : et[3];
        et[4] = (cc == tc[4]) ? e4 : et[4];
        et[5] = (cc == tc[5]) ? e5 : et[5];
        et[6] = (cc == tc[6]) ? e6 : et[6];
        et[7] = (cc == tc[7]) ? e7 : et[7];
        const int loA = __builtin_amdgcn_cvt_pk_fp8_f32(e0, e1, 0, false);
        efA[c] = __builtin_amdgcn_cvt_pk_fp8_f32(e2, e3, loA, true);
        const int loB = __builtin_amdgcn_cvt_pk_fp8_f32(e4, e5, 0, false);
        efB[c] = __builtin_amdgcn_cvt_pk_fp8_f32(e6, e7, loB, true);
    }

    // ---- LDS accumulator init folded before the single exchange barrier ----
    if (tid < NCLS) { s_inter[tid] = 0.f; s_pred[tid] = 0.f; s_cnt[tid] = 0.f; }
    if (tid == 0) s_ce = 0.f;
#pragma unroll
    for (int v = 0; v < 8; ++v)
        s_ex[wave][v][lane] = make_float2(s[v], et[v]);
    __syncthreads();

    float inv[8], pt[8];
#pragma unroll
    for (int v = 0; v < 8; ++v) {
        const float2 q0 = s_ex[0][v][lane];
        const float2 q1 = s_ex[1][v][lane];
        const float2 q2 = s_ex[2][v][lane];
        const float2 q3 = s_ex[3][v][lane];
        const float s1 = (q0.x + q1.x) + (q2.x + q3.x);
        const float e  = (q0.y + q1.y) + (q2.y + q3.y);
        inv[v] = 1.f / s1;
        pt[v]  = e * inv[v];
    }

    // ---- CE + inter/cnt, owner wave only ----
    float ce_acc = 0.f;
#pragma unroll
    for (int v = 0; v < 8; ++v) {
        const bool own = (tc[v] >= cls0) && (tc[v] < cls0 + CPW);
        if (val[v] && own) {
            ce_acc -= __logf(pt[v]);
            atomicAdd(&s_inter[tc[v]], pt[v]);
            atomicAdd(&s_cnt[tc[v]], 1.f);
        }
    }

    // ---- pass B: p^2 per class over 8 voxels, one wave-reduce per class ----
#pragma unroll
    for (int c = 0; c < CPW; ++c) {
        const f2 loA = __builtin_amdgcn_cvt_pk_f32_fp8(efA[c], false);
        const f2 hiA = __builtin_amdgcn_cvt_pk_f32_fp8(efA[c], true);
        const f2 loB = __builtin_amdgcn_cvt_pk_f32_fp8(efB[c], false);
        const f2 hiB = __builtin_amdgcn_cvt_pk_f32_fp8(efB[c], true);
        const float a0 = loA.x * inv[0], a1 = loA.y * inv[1];
        const float a2 = hiA.x * inv[2], a3 = hiA.y * inv[3];
        const float a4 = loB.x * inv[4], a5 = loB.y * inv[5];
        const float a6 = hiB.x * inv[6], a7 = hiB.y * inv[7];
        float sq = ((a0 * a0 + a1 * a1) + (a2 * a2 + a3 * a3))
                 + ((a4 * a4 + a5 * a5) + (a6 * a6 + a7 * a7));
        sq = wave_reduce_sum(sq);
        if (lane == 0) s_pred[cls0 + c] += sq;   // sole owner wave -> plain add
    }
    ce_acc = wave_reduce_sum(ce_acc);
    if (lane == 0) atomicAdd(&s_ce, ce_acc);

    __syncthreads();

    // ---- block partials -> striped global slots ----
    float* wsl = ws + (size_t)(blockIdx.x & (SLOTS - 1)) * WS_PER_SLOT;
    if (tid < NCLS) {
        atomicAdd(&wsl[0 * 176 + b * NCLS + tid], s_inter[tid]);
        atomicAdd(&wsl[1 * 176 + b * NCLS + tid], s_pred[tid]);
        atomicAdd(&wsl[2 * 176 + b * NCLS + tid], s_cnt[tid]);
    }
    if (tid == 0) atomicAdd(&wsl[528], s_ce);
}

__global__ __launch_bounds__(256)
void seg_loss_final(const float* __restrict__ ws, float* __restrict__ out) {
    const int tid = threadIdx.x;
    float dice = 0.f, cnt = 0.f;
    if (tid < 2 * NCLS) {
        float I = 0.f, P = 0.f, G = 0.f;
        for (int s = 0; s < SLOTS; ++s) {
            const float* w = ws + (size_t)s * WS_PER_SLOT;
            I += w[tid]; P += w[176 + tid]; G += w[352 + tid];
        }
        dice = 1.f - (2.f * I + SMOOTH) / (G + P + SMOOTH);
        cnt  = G;
    }
    float ce_s = 0.f;
    if (tid < SLOTS) ce_s = ws[(size_t)tid * WS_PER_SLOT + 528];

    dice = wave_reduce_sum(dice);
    cnt  = wave_reduce_sum(cnt);
    ce_s = wave_reduce_sum(ce_s);

    __shared__ float sd[4], sc2[4], se[4];
    const int w = tid >> 6, l = tid & 63;
    if (l == 0) { sd[w] = dice; sc2[w] = cnt; se[w] = ce_s; }
    __syncthreads();
    if (tid == 0) {
        const float D  = sd[0] + sd[1] + sd[2] + sd[3];
        const float Cn = sc2[0] + sc2[1] + sc2[2] + sc2[3];
        const float CE = (se[0] + se[1] + se[2] + se[3]) / fmaxf(Cn, 1.0f);
        out[0] = 0.4f * CE + 0.6f * (D / 176.f);
    }
}

extern "C" void kernel_launch(void* const* d_in, const int* in_sizes, int n_in,
                              void* d_out, int out_size, void* d_ws, size_t ws_size,
                              hipStream_t stream) {
    const float* pred = (const float*)d_in[0];
    const int*   tgt  = (const int*)d_in[1];
    float* ws = (float*)d_ws;

    (void)hipMemsetAsync(d_ws, 0, SLOTS * WS_PER_SLOT * sizeof(float), stream);
    seg_loss_main<<<2 * BLOCKS_PER_B, TPB, 0, stream>>>(pred, tgt, ws);
    seg_loss_final<<<1, 256, 0, stream>>>(ws, (float*)d_out);
}

// Round 11
// 140.854 us; speedup vs baseline: 1.7588x; 1.7588x over previous
//
#include <hip/hip_runtime.h>

#define NCLS 88
#define DHW (96 * 96 * 96)            // 884736
#define TPB 256                       // 4 waves, 4-way class split
#define WAVES 4
#define CPW 22                        // classes per wave
#define VOX_PER_BLOCK 256             // 4 voxels per lane, one float4 group
#define BLOCKS_PER_B (DHW / VOX_PER_BLOCK)   // 3456, exact
#define SLOTS 32
#define SMOOTH 1e-5f
#define WS_PER_SLOT 529
// ws layout per slot: [0..176) inter[b*88+c] | [176..352) pred_o | [352..528) cnt | [528] ce

typedef float f2 __attribute__((ext_vector_type(2)));

__device__ __forceinline__ float wave_reduce_sum(float v) {
#pragma unroll
    for (int i = 1; i < 64; i <<= 1)
        v += __shfl_xor(v, i, 64);
    return v;
}

// NOTE: no min-waves arg — __launch_bounds__(TPB,N) forced 64-VGPR + ~1.5 GB
// spill traffic in R4/R6. Short block, minimal state: target ~64-75 VGPR.
__global__ __launch_bounds__(TPB)
void seg_loss_main(const float* __restrict__ pred, const int* __restrict__ tgt,
                   float* __restrict__ ws) {
    __shared__ float s_inter[NCLS];
    __shared__ float s_pred[NCLS];
    __shared__ float s_cnt[NCLS];
    __shared__ float s_ce;
    __shared__ float2 s_ex[WAVES][4][64];  // [wave][vox][lane] = {s1_part, et_part}, 8 KB

    const int tid  = threadIdx.x;
    const int lane = tid & 63;
    const int wave = tid >> 6;                 // 0..3
    const int b    = blockIdx.x / BLOCKS_PER_B;
    const int base = (blockIdx.x % BLOCKS_PER_B) * VOX_PER_BLOCK;
    const int cls0 = wave * CPW;
    const float* pb = pred + (size_t)b * NCLS * DHW + (size_t)cls0 * DHW;
    const int*   tb = tgt  + (size_t)b * DHW;

    // ---- targets: 4 voxels per lane, coalesced int4 ----
    const int4 t4 = *(const int4*)(tb + base + lane * 4);
    const int tv[4] = { t4.x, t4.y, t4.z, t4.w };
    bool val[4]; int tc[4]; float vf[4];
#pragma unroll
    for (int v = 0; v < 4; ++v) {
        val[v] = (tv[v] != -1);
        tc[v]  = val[v] ? tv[v] : 0;
        vf[v]  = val[v] ? 1.f : 0.f;
    }

    // ---- pass A: 22 classes x float4 (4 voxels/lane), fp8-packed exps ----
    const float* p = pb + base + lane * 4;
    float s[4]  = {0, 0, 0, 0};
    float et[4] = {0, 0, 0, 0};
    int ef[CPW];
#pragma unroll
    for (int c = 0; c < CPW; ++c) {
        const float4 x = *(const float4*)(p + (size_t)c * DHW);
        const float e0 = __expf(x.x * vf[0]);
        const float e1 = __expf(x.y * vf[1]);
        const float e2 = __expf(x.z * vf[2]);
        const float e3 = __expf(x.w * vf[3]);
        s[0] += e0; s[1] += e1; s[2] += e2; s[3] += e3;
        const int cc = cls0 + c;
        et[0] = (cc == tc[0]) ? e0 : et[0];
        et[1] = (cc == tc[1]) ? e1 : et[1];
        et[2] = (cc == tc[2]) ? e2 : et[2];
        et[3] = (cc == tc[3]) ? e3 : et[3];
        const int lo = __builtin_amdgcn_cvt_pk_fp8_f32(e0, e1, 0, false);
        ef[c] = __builtin_amdgcn_cvt_pk_fp8_f32(e2, e3, lo, true);
    }

    // ---- LDS init folded before the single exchange barrier ----
    if (tid < NCLS) { s_inter[tid] = 0.f; s_pred[tid] = 0.f; s_cnt[tid] = 0.f; }
    if (tid == 0) s_ce = 0.f;
#pragma unroll
    for (int v = 0; v < 4; ++v)
        s_ex[wave][v][lane] = make_float2(s[v], et[v]);
    __syncthreads();

    float inv[4], pt[4];
#pragma unroll
    for (int v = 0; v < 4; ++v) {
        const float2 q0 = s_ex[0][v][lane];
        const float2 q1 = s_ex[1][v][lane];
        const float2 q2 = s_ex[2][v][lane];
        const float2 q3 = s_ex[3][v][lane];
        const float s1 = (q0.x + q1.x) + (q2.x + q3.x);
        const float e  = (q0.y + q1.y) + (q2.y + q3.y);
        inv[v] = 1.f / s1;
        pt[v]  = e * inv[v];
    }

    // ---- CE + inter/cnt, owner wave only ----
    float ce_acc = 0.f;
#pragma unroll
    for (int v = 0; v < 4; ++v) {
        const bool own = (tc[v] >= cls0) && (tc[v] < cls0 + CPW);
        if (val[v] && own) {
            ce_acc -= __logf(pt[v]);
            atomicAdd(&s_inter[tc[v]], pt[v]);
            atomicAdd(&s_cnt[tc[v]], 1.f);
        }
    }

    // ---- pass B: p^2 per class over 4 voxels, one wave-reduce per class ----
#pragma unroll
    for (int c = 0; c < CPW; ++c) {
        const f2 lo = __builtin_amdgcn_cvt_pk_f32_fp8(ef[c], false);
        const f2 hi = __builtin_amdgcn_cvt_pk_f32_fp8(ef[c], true);
        const float a0 = lo.x * inv[0], a1 = lo.y * inv[1];
        const float a2 = hi.x * inv[2], a3 = hi.y * inv[3];
        float sq = (a0 * a0 + a1 * a1) + (a2 * a2 + a3 * a3);
        sq = wave_reduce_sum(sq);
        if (lane == 0) s_pred[cls0 + c] += sq;   // sole owner wave -> plain add
    }
    ce_acc = wave_reduce_sum(ce_acc);
    if (lane == 0) atomicAdd(&s_ce, ce_acc);

    __syncthreads();

    // ---- block partials -> striped global slots ----
    float* wsl = ws + (size_t)(blockIdx.x & (SLOTS - 1)) * WS_PER_SLOT;
    if (tid < NCLS) {
        atomicAdd(&wsl[0 * 176 + b * NCLS + tid], s_inter[tid]);
        atomicAdd(&wsl[1 * 176 + b * NCLS + tid], s_pred[tid]);
        atomicAdd(&wsl[2 * 176 + b * NCLS + tid], s_cnt[tid]);
    }
    if (tid == 0) atomicAdd(&wsl[528], s_ce);
}

__global__ __launch_bounds__(256)
void seg_loss_final(const float* __restrict__ ws, float* __restrict__ out) {
    const int tid = threadIdx.x;
    float dice = 0.f, cnt = 0.f;
    if (tid < 2 * NCLS) {
        float I = 0.f, P = 0.f, G = 0.f;
        for (int s = 0; s < SLOTS; ++s) {
            const float* w = ws + (size_t)s * WS_PER_SLOT;
            I += w[tid]; P += w[176 + tid]; G += w[352 + tid];
        }
        dice = 1.f - (2.f * I + SMOOTH) / (G + P + SMOOTH);
        cnt  = G;
    }
    float ce_s = 0.f;
    if (tid < SLOTS) ce_s = ws[(size_t)tid * WS_PER_SLOT + 528];

    dice = wave_reduce_sum(dice);
    cnt  = wave_reduce_sum(cnt);
    ce_s = wave_reduce_sum(ce_s);

    __shared__ float sd[4], sc2[4], se[4];
    const int w = tid >> 6, l = tid & 63;
    if (l == 0) { sd[w] = dice; sc2[w] = cnt; se[w] = ce_s; }
    __syncthreads();
    if (tid == 0) {
        const float D  = sd[0] + sd[1] + sd[2] + sd[3];
        const float Cn = sc2[0] + sc2[1] + sc2[2] + sc2[3];
        const float CE = (se[0] + se[1] + se[2] + se[3]) / fmaxf(Cn, 1.0f);
        out[0] = 0.4f * CE + 0.6f * (D / 176.f);
    }
}

extern "C" void kernel_launch(void* const* d_in, const int* in_sizes, int n_in,
                              void* d_out, int out_size, void* d_ws, size_t ws_size,
                              hipStream_t stream) {
    const float* pred = (const float*)d_in[0];
    const int*   tgt  = (const int*)d_in[1];
    float* ws = (float*)d_ws;

    (void)hipMemsetAsync(d_ws, 0, SLOTS * WS_PER_SLOT * sizeof(float), stream);
    seg_loss_main<<<2 * BLOCKS_PER_B, TPB, 0, stream>>>(pred, tgt, ws);
    seg_loss_final<<<1, 256, 0, stream>>>(ws, (float*)d_out);
}